// Round 10
// baseline (2476.778 us; speedup 1.0000x reference)
//
#include <hip/hip_runtime.h>
#include <hip/hip_bf16.h>

// NonlinearReservoirCell: B=262144 rows, M=3 independent tiny MLPs
//   free_water = last_free_water + sum_n runoff
//   a1 = relu(runoff @ W1 + b1)   (256 -> 256)
//   a2 = relu(a1 @ W2 + b2)       (256 -> 128)
//   ratio = sigmoid(a2 @ W3 + b3) (128 -> 1)
//   flow = fw*ratio + last_flow*(1-ratio);  new_fw = fw - flow
// R10: R9 (dense rows, verified) + T14 async-stage split:
//   issue u+1's 24 runoff loads at m=0 compute start (regs),
//   cvt->bf16 at m=1 start, write into the single sXP panel after m=2's L1
//   (last reader) behind one barrier. HBM latency hides under ~2 m-passes;
//   stage leaves the critical path. Same LDS (66 KB), 2 blocks/CU.

#define B_TOT 262144
#define M_    3
#define N_    256
#define H1_   256
#define H2_   128
#define BM_   (B_TOT * M_)
#define ROWS_BLK 512
#define UNITS    16

typedef __bf16 bf16_t;
typedef __bf16  bf16x8 __attribute__((ext_vector_type(8)));
typedef float   f32x16 __attribute__((ext_vector_type(16)));
typedef float   f32x4  __attribute__((ext_vector_type(4)));

__device__ __forceinline__ unsigned pack_bf2(float lo, float hi) {
  union { bf16_t b; unsigned short u; } a, c;
  a.b = (bf16_t)lo; c.b = (bf16_t)hi;
  return ((unsigned)c.u << 16) | (unsigned)a.u;
}

// ---------------------------------------------------------------------------
// Prep: transpose + cvt weights into per-lane MFMA A-fragment order (bf16).
// w1s[m][kk(16)][t(8)][lane(64)][ii(8)] = bf16(W1[m][n=16kk+8*(lane>>5)+ii][h=32t+(lane&31)])
// w2s[m][kk2(16)][t2(4)][lane(64)][ii(8)] = bf16(W2[m][h=16kk2+8*(lane>>5)+ii][k2=32t2+(lane&31)])
// ---------------------------------------------------------------------------
__global__ __launch_bounds__(256) void prep_weights(
    const float* __restrict__ W1, const float* __restrict__ W2,
    bf16_t* __restrict__ w1s, bf16_t* __restrict__ w2s)
{
  int id = blockIdx.x * 256 + threadIdx.x;
  const int NW1 = M_ * 16 * 8 * 64;   // 24576 groups of 8
  const int NW2 = M_ * 16 * 4 * 64;   // 12288 groups of 8
  if (id < NW1) {
    int lane = id & 63;
    int t    = (id >> 6) & 7;
    int kk   = (id >> 9) & 15;
    int m    = id >> 13;
    int h  = 32 * t + (lane & 31);
    int n0 = 16 * kk + 8 * (lane >> 5);
    bf16x8 v;
#pragma unroll
    for (int ii = 0; ii < 8; ++ii)
      v[ii] = (bf16_t)W1[((size_t)m * N_ + (n0 + ii)) * H1_ + h];
    *reinterpret_cast<bf16x8*>(&w1s[(size_t)id * 8]) = v;
  } else if (id < NW1 + NW2) {
    int j    = id - NW1;
    int lane = j & 63;
    int t2   = (j >> 6) & 3;
    int kk2  = (j >> 8) & 15;
    int m    = j >> 12;
    int k2 = 32 * t2 + (lane & 31);
    int h0 = 16 * kk2 + 8 * (lane >> 5);
    bf16x8 v;
#pragma unroll
    for (int ii = 0; ii < 8; ++ii)
      v[ii] = (bf16_t)W2[((size_t)m * H1_ + (h0 + ii)) * H2_ + k2];
    *reinterpret_cast<bf16x8*>(&w2s[(size_t)j * 8]) = v;
  }
}

// ---------------------------------------------------------------------------
// Main kernel. grid = 512, block = 4 waves, 2 blocks/CU. Block owns 512 rows,
// 16 units of 32 rows x all 3 m. Wave wv: L1 h-slice [64wv,64wv+64),
// L2 k2-slice [32wv,32wv+32).
// ---------------------------------------------------------------------------
__global__ __launch_bounds__(256, 2) void reservoir_kernel(
    const float* __restrict__ last_flow,
    const float* __restrict__ last_fw,
    const float* __restrict__ runoff,
    const float* __restrict__ b1,
    const float* __restrict__ b2,
    const float* __restrict__ W3,
    const float* __restrict__ b3,
    const bf16_t* __restrict__ w1s,
    const bf16_t* __restrict__ w2s,
    float* __restrict__ out)
{
  // sXP: [32 rows][768 bf16] (full 3-KB rows as bf16). 16-B granules,
  // phys = mgroup*32 + (j ^ row). 48 KB, single-buffered (write-late).
  __shared__ alignas(16) bf16_t sXP[32 * 768];
  // sY: [32 rows][256 bf16] a1 panel, R7-verified swizzle. 16 KB.
  __shared__ alignas(16) bf16_t sY[32 * 256];
  __shared__ float sPart[M_][4][32];
  __shared__ float sRsum[M_][32];

  const int tid  = threadIdx.x;
  const int lane = tid & 63;
  const int wv   = tid >> 6;
  const int hi   = lane >> 5;
  const int r    = lane & 31;
  const int r15  = r & 15;

  const size_t rbase = (size_t)blockIdx.x * ROWS_BLK;

  // ---- prologue: stage unit 0 directly ----
  {
    const float* src = runoff + rbase * (M_ * N_);
#pragma unroll
    for (int c = 0; c < 12; ++c) {
      const int s   = c * 256 + tid;        // 32-B chunk index in [0,3072)
      const int row = s / 96;               // 96 chunks per 3-KB row
      const int c32 = s - row * 96;
      f32x4 va = __builtin_nontemporal_load(
          reinterpret_cast<const f32x4*>(src + (size_t)s * 8));
      f32x4 vb = __builtin_nontemporal_load(
          reinterpret_cast<const f32x4*>(src + (size_t)s * 8 + 4));
      uint4 d;
      d.x = pack_bf2(va[0], va[1]);
      d.y = pack_bf2(va[2], va[3]);
      d.z = pack_bf2(vb[0], vb[1]);
      d.w = pack_bf2(vb[2], vb[3]);
      const int mg   = c32 >> 5;
      const int j    = c32 & 31;
      const int phys = mg * 32 + (j ^ row);
      *reinterpret_cast<uint4*>(&sXP[row * 768 + phys * 8]) = d;
    }
  }
  __syncthreads();   // unit 0 panel ready

  f32x4 fA[12], fB[12];   // prefetch transients (96 VGPR, live m0->m1)
  uint4 preU[12];         // packed bf16   (48 VGPR, live m1->m2)

  for (int u = 0; u < UNITS; ++u) {
    const bool pf = (u + 1 < UNITS);

    // ---- T14 issue-early: unit u+1's 24 loads, before any compute ----
    if (pf) {
      const float* nsrc = runoff + (rbase + (u + 1) * 32) * (M_ * N_);
#pragma unroll
      for (int c = 0; c < 12; ++c) {
        const int s = c * 256 + tid;
        fA[c] = __builtin_nontemporal_load(
            reinterpret_cast<const f32x4*>(nsrc + (size_t)s * 8));
        fB[c] = __builtin_nontemporal_load(
            reinterpret_cast<const f32x4*>(nsrc + (size_t)s * 8 + 4));
      }
      __builtin_amdgcn_sched_barrier(0);   // pin issue point
    }

#pragma unroll
    for (int m = 0; m < M_; ++m) {
      // ---- cvt prefetched data at m=1 start (latency long gone) ----
      if (m == 1 && pf) {
#pragma unroll
        for (int c = 0; c < 12; ++c) {
          preU[c].x = pack_bf2(fA[c][0], fA[c][1]);
          preU[c].y = pack_bf2(fA[c][2], fA[c][3]);
          preU[c].z = pack_bf2(fB[c][0], fB[c][1]);
          preU[c].w = pack_bf2(fB[c][2], fB[c][3]);
        }
      }

      const bf16_t* w1m = w1s + (size_t)m * 65536;
      const bf16_t* w2m = w2s + (size_t)m * 32768;

      // ---------------- Layer 1: h-slice [64wv, 64wv+64) ----------------
      f32x16 a0 = f32x16{}, a1m = f32x16{};
      float rs = 0.f;
#pragma unroll
      for (int half = 0; half < 2; ++half) {
        bf16x8 wf[8][2];
#pragma unroll
        for (int k = 0; k < 8; ++k)
#pragma unroll
          for (int tl = 0; tl < 2; ++tl)
            wf[k][tl] = *reinterpret_cast<const bf16x8*>(
                w1m + (size_t)(half * 8 + k) * 4096 + (2 * wv + tl) * 512 + lane * 8);
#pragma unroll
        for (int k = 0; k < 8; ++k) {
          const int kk = half * 8 + k;
          const int j  = 2 * kk + hi;
          bf16x8 bf = *reinterpret_cast<const bf16x8*>(
              &sXP[r * 768 + (m * 32 + (j ^ r)) * 8]);
          if (wv == m) {
#pragma unroll
            for (int i = 0; i < 8; ++i) rs += (float)bf[i];
          }
          a0  = __builtin_amdgcn_mfma_f32_32x32x16_bf16(wf[k][0], bf, a0, 0, 0, 0);
          a1m = __builtin_amdgcn_mfma_f32_32x32x16_bf16(wf[k][1], bf, a1m, 0, 0, 0);
        }
      }
      if (wv == m) {
        rs += __shfl_xor(rs, 32, 64);
        if (hi == 0) sRsum[m][r] = rs;
      }

      // ---- T14 write-late: after the LAST sXP reader (m=2's L1) ----
      if (m == 2) {
        __syncthreads();   // bar W: all waves done reading sXP(u)
        if (pf) {
#pragma unroll
          for (int c = 0; c < 12; ++c) {
            const int s   = c * 256 + tid;
            const int row = s / 96;
            const int c32 = s - row * 96;
            const int mg   = c32 >> 5;
            const int j    = c32 & 31;
            const int phys = mg * 32 + (j ^ row);
            *reinterpret_cast<uint4*>(&sXP[row * 768 + phys * 8]) = preU[c];
          }
        }
      }

      // a1 = relu(acc + b1) -> sY (R7-verified mapping & swizzle)
      const float* b1m = b1 + m * H1_;
#pragma unroll
      for (int tl = 0; tl < 2; ++tl) {
        const int tg = 2 * wv + tl;
        const f32x16& ac = (tl == 0) ? a0 : a1m;
#pragma unroll
        for (int g2 = 0; g2 < 4; ++g2) {
          const int hb = 32 * tg + 8 * g2 + 4 * hi;
          f32x4 bv = *reinterpret_cast<const f32x4*>(&b1m[hb]);
          uint2 d;
          d.x = pack_bf2(fmaxf(ac[4 * g2 + 0] + bv[0], 0.f),
                         fmaxf(ac[4 * g2 + 1] + bv[1], 0.f));
          d.y = pack_bf2(fmaxf(ac[4 * g2 + 2] + bv[2], 0.f),
                         fmaxf(ac[4 * g2 + 3] + bv[3], 0.f));
          const int G = 4 * tg + g2;
          *reinterpret_cast<uint2*>(
              &sY[r * 256 + ((G ^ r15) * 8) + hi * 4]) = d;
        }
      }
      __syncthreads();   // bar Y1: sY complete (and sXP(u+1) if m==2)

      // ---------------- Layer 2: k2-slice [32wv, 32wv+32) ----------------
      bf16x8 w2f[16];
#pragma unroll
      for (int kk2 = 0; kk2 < 16; ++kk2)
        w2f[kk2] = *reinterpret_cast<const bf16x8*>(
            w2m + (size_t)kk2 * 2048 + wv * 512 + lane * 8);
      f32x16 c2 = f32x16{};
#pragma unroll
      for (int kk2 = 0; kk2 < 16; ++kk2) {
        bf16x8 bf = *reinterpret_cast<const bf16x8*>(
            &sY[r * 256 + (((2 * kk2 + hi) ^ r15) * 8)]);
        c2 = __builtin_amdgcn_mfma_f32_32x32x16_bf16(w2f[kk2], bf, c2, 0, 0, 0);
      }

      // ---------------- Layer 3 partial ----------------
      const float* b2m = b2 + m * H2_;
      const float* w3m = W3 + m * H2_;
      float part = 0.f;
#pragma unroll
      for (int e = 0; e < 16; ++e) {
        const int k2 = 32 * wv + (e & 3) + 8 * (e >> 2) + 4 * hi;
        part += fmaxf(c2[e] + b2m[k2], 0.f) * w3m[k2];
      }
      part += __shfl_xor(part, 32, 64);
      if (hi == 0) sPart[m][wv][r] = part;
      __syncthreads();   // bar Y2: partials + rsum visible

      // ---------------- epilogue: one thread per row ----------------
      if (tid < 32) {
        const size_t grow = rbase + u * 32 + tid;
        const size_t oi   = grow * M_ + m;
        const float pt    = sPart[m][0][tid] + sPart[m][1][tid]
                          + sPart[m][2][tid] + sPart[m][3][tid] + b3[m];
        const float ratio = 1.0f / (1.0f + __expf(-pt));
        const float fw    = last_fw[oi] + sRsum[m][tid];
        const float lf    = last_flow[oi];
        const float flow  = fw * ratio + lf * (1.0f - ratio);
        out[oi]       = fw - flow;   // new_free_water
        out[BM_ + oi] = flow;        // flow
      }
    }
  }
}

// ---------------------------------------------------------------------------
extern "C" void kernel_launch(void* const* d_in, const int* in_sizes, int n_in,
                              void* d_out, int out_size, void* d_ws, size_t ws_size,
                              hipStream_t stream) {
  const float* last_flow = (const float*)d_in[0];
  const float* last_fw   = (const float*)d_in[1];
  const float* runoff    = (const float*)d_in[2];
  const float* W1 = (const float*)d_in[3];
  const float* b1 = (const float*)d_in[4];
  const float* W2 = (const float*)d_in[5];
  const float* b2 = (const float*)d_in[6];
  const float* W3 = (const float*)d_in[7];
  const float* b3 = (const float*)d_in[8];
  float* out = (float*)d_out;

  bf16_t* w1s = (bf16_t*)d_ws;                    // 3*65536 bf16 = 384 KB
  bf16_t* w2s = w1s + (size_t)M_ * 65536;         // 3*32768 bf16 = 192 KB

  prep_weights<<<144, 256, 0, stream>>>(W1, W2, w1s, w2s);

  reservoir_kernel<<<B_TOT / ROWS_BLK, 256, 0, stream>>>(
      last_flow, last_fw, runoff, b1, b2, W3, b3, w1s, w2s, out);
}